// Round 8
// baseline (761.358 us; speedup 1.0000x reference)
//
#include <hip/hip_runtime.h>
#include <hip/hip_bf16.h>

#define NN 100000
#define NE 300000
#define NG 2000
#define DD 256
#define NL 5
#define BN_EPS 1e-5f

typedef __bf16 bf16x8 __attribute__((ext_vector_type(8)));
typedef float floatx16 __attribute__((ext_vector_type(16)));

__device__ inline unsigned short f2bf(float x) {
  unsigned int u = __builtin_bit_cast(unsigned int, x);
  unsigned int r = u + 0x7FFFu + ((u >> 16) & 1u);
  return (unsigned short)(r >> 16);
}
__device__ inline float bf2f(unsigned short u) {
  return __builtin_bit_cast(float, (unsigned int)u << 16);
}
__device__ inline float blo(unsigned int v) {
  return __builtin_bit_cast(float, v << 16);
}
__device__ inline float bhi(unsigned int v) {
  return __builtin_bit_cast(float, v & 0xFFFF0000u);
}
__device__ inline unsigned int pack2(float a, float b) {
  return (unsigned int)f2bf(a) | ((unsigned int)f2bf(b) << 16);
}

// ---- weight pack (coalesced LDS-transpose) + vn init + cursor/t0f zero ----
#define WBLK (18 * 64)
__global__ __launch_bounds__(256) void k_pack_all(
    const float* __restrict__ gw1, const float* __restrict__ gw2,
    const float* __restrict__ vw1, const float* __restrict__ vw2,
    unsigned short* __restrict__ Wf,
    const float* __restrict__ vnw, unsigned short* __restrict__ vnb,
    int* __restrict__ cursor, float* __restrict__ t0f) {
  int bb = blockIdx.x;
  int tid = threadIdx.x;
  if (bb < WBLK) {
    __shared__ float sh[16][65];  // +1 pad: conflict-free column reads
    int m = bb >> 6;        // matrix 0..17
    int tile = bb & 63;
    int kt = tile >> 2;     // 16 k-tiles of 16
    int nt4 = tile & 3;     // 4 n-tiles of 64
    const float* W;
    int mm;
    if (m < 5) { W = gw1; mm = m; }
    else if (m < 10) { W = gw2; mm = m - 5; }
    else if (m < 14) { W = vw1; mm = m - 10; }
    else { W = vw2; mm = m - 14; }
    int k0 = kt * 16, n0 = nt4 * 64;
    int kk = tid >> 4, c4 = (tid & 15) << 2;
    *(float4*)&sh[kk][c4] =
        *(const float4*)(W + (size_t)mm * 65536 + (k0 + kk) * 256 + n0 + c4);
    __syncthreads();
    if (tid < 128) {
      int lh = tid >> 6, nn = tid & 63;
      unsigned short o[8];
#pragma unroll
      for (int j = 0; j < 8; ++j) o[j] = f2bf(sh[lh * 8 + j][nn]);
      int lane = lh * 32 + (nn & 31);
      int ntg = (n0 + nn) >> 5;
      size_t off = (size_t)m * 65536 + ntg * 8192 + kt * 512 + lane * 8;
      *(uint4*)(Wf + off) = *(uint4*)o;
    }
    return;
  }
  int i = (bb - WBLK) * 256 + tid;
  if (i < NG * DD) { vnb[i] = f2bf(vnw[i & (DD - 1)]); return; }
  i -= NG * DD;
  if (i < NN) { cursor[i] = 0; return; }
  i -= NN;
  if (i < NG * DD) t0f[i] = 0.f;
}

// ---------------- CSR build ----------------
__global__ __launch_bounds__(256) void k_hist(const int* __restrict__ dst,
                                              int* __restrict__ cnt) {
  int e = blockIdx.x * 256 + threadIdx.x;
  if (e < NE) atomicAdd(&cnt[dst[e]], 1);
}

__global__ __launch_bounds__(1024) void k_bsum(const int* __restrict__ cnt,
                                               int* __restrict__ bsum) {
  __shared__ int sh[1024];
  int t = threadIdx.x, idx = blockIdx.x * 1024 + t;
  sh[t] = (idx < NN) ? cnt[idx] : 0;
  __syncthreads();
  for (int off = 512; off > 0; off >>= 1) {
    if (t < off) sh[t] += sh[t + off];
    __syncthreads();
  }
  if (t == 0) bsum[blockIdx.x] = sh[0];
}

__global__ __launch_bounds__(128) void k_scanb(const int* __restrict__ bsum,
                                               int* __restrict__ bbase, int nb) {
  __shared__ int sh[128];
  int t = threadIdx.x;
  sh[t] = (t < nb) ? bsum[t] : 0;
  __syncthreads();
  if (t == 0) {
    int run = 0;
    for (int i = 0; i < nb; ++i) { int v = sh[i]; sh[i] = run; run += v; }
  }
  __syncthreads();
  if (t < nb) bbase[t] = sh[t];
}

__global__ __launch_bounds__(1024) void k_rowptr(const int* __restrict__ cnt,
                                                 const int* __restrict__ bbase,
                                                 int* __restrict__ rowptr,
                                                 int* __restrict__ cursor) {
  __shared__ int sh[1024];
  int t = threadIdx.x, idx = blockIdx.x * 1024 + t;
  int v = (idx < NN) ? cnt[idx] : 0;
  sh[t] = v;
  __syncthreads();
  for (int off = 1; off < 1024; off <<= 1) {
    int add = (t >= off) ? sh[t - off] : 0;
    __syncthreads();
    sh[t] += add;
    __syncthreads();
  }
  if (idx < NN) {
    int excl = sh[t] - v + bbase[blockIdx.x];
    rowptr[idx] = excl;
    cursor[idx] = excl;
  }
  if (blockIdx.x == 0 && t == 0) rowptr[NN] = NE;
}

// writes (src, batch[src]) so the fused gather has no dependent load chain
__global__ __launch_bounds__(256) void k_fill_src(const int* __restrict__ src,
                                                  const int* __restrict__ dst,
                                                  const int* __restrict__ batch,
                                                  int* __restrict__ cursor,
                                                  int2* __restrict__ ssrc2) {
  int e = blockIdx.x * 256 + threadIdx.x;
  if (e >= NE) return;
  int s = src[e];
  int pos = atomicAdd(&cursor[dst[e]], 1);
  ssrc2[pos] = make_int2(s, batch[s]);
}

// ---------------- node encode -> bf16 (16 nodes/block, w in LDS) ----------------
__global__ __launch_bounds__(256) void k_node_encode(
    const float* __restrict__ x, const float* __restrict__ w,
    const float* __restrict__ b, unsigned short* __restrict__ h16) {
  __shared__ float ws[20][256];
  __shared__ float xr[16][20];
  int tid = threadIdx.x;
  int n0 = blockIdx.x * 16;
  for (int p = tid; p < 20 * 64; p += 256) {
    int k = p >> 6, c4 = (p & 63) << 2;
    *(float4*)&ws[k][c4] = *(const float4*)(w + k * 256 + c4);
  }
  for (int p = tid; p < 320; p += 256) {
    int nn = p / 20, k = p - nn * 20;
    xr[nn][k] = x[(size_t)(n0 + nn) * 20 + k];
  }
  __syncthreads();
  int ln = tid >> 6, c4 = (tid & 63) << 2;
  float4 bv = *(const float4*)(b + c4);
  float a[4][4];
#pragma unroll
  for (int nn = 0; nn < 4; ++nn) {
    a[nn][0] = bv.x; a[nn][1] = bv.y; a[nn][2] = bv.z; a[nn][3] = bv.w;
  }
#pragma unroll
  for (int k = 0; k < 20; ++k) {
    float4 wv = *(float4*)&ws[k][c4];
#pragma unroll
    for (int nn = 0; nn < 4; ++nn) {
      float xv = xr[ln * 4 + nn][k];
      a[nn][0] = fmaf(xv, wv.x, a[nn][0]);
      a[nn][1] = fmaf(xv, wv.y, a[nn][1]);
      a[nn][2] = fmaf(xv, wv.z, a[nn][2]);
      a[nn][3] = fmaf(xv, wv.w, a[nn][3]);
    }
  }
#pragma unroll
  for (int nn = 0; nn < 4; ++nn) {
    int n = n0 + ln * 4 + nn;
    *(ushort4*)(h16 + (size_t)n * DD + c4) =
        make_ushort4(f2bf(a[nn][0]), f2bf(a[nn][1]), f2bf(a[nn][2]), f2bf(a[nn][3]));
  }
}

// ------------- fused GIN layer (1024 threads, 64 rows/block) -------------
// Gather is byte-identical to R6's proven 16-thr/row form (no unroll - R7
// showed x2 unroll is neutral; no prefetch; no swizzle). The ONLY structural
// change: 64 rows/block via 1024 threads -> 1563 blocks, halving the per-
// dispatch weight L2 stream (800->400 MB); the two row-half waves sharing a
// column slab read identical weight addresses (L1 reuse). Occupancy math
// unchanged: 2 blocks/CU x 16 waves = 32 waves/CU (the cap either way).
__global__ __launch_bounds__(1024) void k_gin_layer(
    const unsigned short* __restrict__ hin, const unsigned short* __restrict__ vnb,
    const int2* __restrict__ ssrc2, const int* __restrict__ batch,
    const int* __restrict__ rowptr,
    const unsigned short* __restrict__ Wf1, const float* __restrict__ b1,
    const unsigned short* __restrict__ Wf2, const float* __restrict__ b2,
    const float* __restrict__ bng, const float* __restrict__ bnb,
    const float* __restrict__ bnm, const float* __restrict__ bnv,
    unsigned short* __restrict__ hout, float* __restrict__ t0f) {
  __shared__ unsigned short As[16][2][64][8];  // 32 KB z fragments
  __shared__ unsigned short Bs[16][2][64][8];  // 32 KB hid fragments
  __shared__ int gsh[64];
  int tid = threadIdx.x;
  int m0 = blockIdx.x * 64;      // 1563 blocks; last block is half-padded
  int r = tid >> 4, q = tid & 15;  // row 0..63, col chunk 0..15
  int m = m0 + r;
  bool valid = (m < NN);
  int cb = q << 4;               // col base (16 cols per thread)
  if (tid < 64) {
    int mg = m0 + tid;
    gsh[tid] = batch[mg < NN ? mg : NN - 1];
  }
  {
    float acc[16];
#pragma unroll
    for (int i = 0; i < 16; ++i) acc[i] = 0.f;
#define ACC8(off, H, V)                                \
  acc[(off) + 0] += blo((H).x) + blo((V).x);           \
  acc[(off) + 1] += bhi((H).x) + bhi((V).x);           \
  acc[(off) + 2] += blo((H).y) + blo((V).y);           \
  acc[(off) + 3] += bhi((H).y) + bhi((V).y);           \
  acc[(off) + 4] += blo((H).z) + blo((V).z);           \
  acc[(off) + 5] += bhi((H).z) + bhi((V).z);           \
  acc[(off) + 6] += blo((H).w) + blo((V).w);           \
  acc[(off) + 7] += bhi((H).w) + bhi((V).w);
    if (valid) {
      int bm = batch[m];
      const unsigned short* hp = hin + (size_t)m * DD + cb;
      const unsigned short* vp = vnb + (size_t)bm * DD + cb;
      uint4 h0 = *(const uint4*)hp, h1 = *(const uint4*)(hp + 8);
      uint4 v0 = *(const uint4*)vp, v1 = *(const uint4*)(vp + 8);
      ACC8(0, h0, v0) ACC8(8, h1, v1)
      int b = rowptr[m], e = rowptr[m + 1];
      for (int t = b; t < e; ++t) {
        int2 sp = ssrc2[t];
        const unsigned short* hp2 = hin + (size_t)sp.x * DD + cb;
        const unsigned short* vp2 = vnb + (size_t)sp.y * DD + cb;
        uint4 h2 = *(const uint4*)hp2, h3 = *(const uint4*)(hp2 + 8);
        uint4 v2 = *(const uint4*)vp2, v3 = *(const uint4*)(vp2 + 8);
        ACC8(0, h2, v2) ACC8(8, h3, v3)
      }
    }
#undef ACC8
    // cols cb+i*8+j -> fragment [ks=q][lh=i][row=r][j]
#pragma unroll
    for (int i = 0; i < 2; ++i) {
      uint4 o;
      o.x = pack2(acc[i * 8 + 0], acc[i * 8 + 1]);
      o.y = pack2(acc[i * 8 + 2], acc[i * 8 + 3]);
      o.z = pack2(acc[i * 8 + 4], acc[i * 8 + 5]);
      o.w = pack2(acc[i * 8 + 6], acc[i * 8 + 7]);
      *(uint4*)&As[q][i][r][0] = o;
    }
  }
  __syncthreads();

  int wave = tid >> 6, lane = tid & 63;  // wave in [0,16)
  int cslab = wave & 7, rh = wave >> 3;  // col slab 0..7, row half 0..1
  int lrow = lane & 31, lhi = lane >> 5;
  int c = cslab * 32 + lrow;
  int rbase = rh * 32;

  // ---- phase 2: hid = relu(z @ W1 + b1) -> Bs ----
  {
    floatx16 facc = (floatx16)(0.f);
    const bf16x8* wf = (const bf16x8*)Wf1;
#pragma unroll
    for (int ks = 0; ks < 16; ++ks) {
      bf16x8 a = *(const bf16x8*)&As[ks][lhi][rbase + lrow][0];
      bf16x8 bb = wf[((cslab * 16 + ks) << 6) + lane];
      facc = __builtin_amdgcn_mfma_f32_32x32x16_bf16(a, bb, facc, 0, 0, 0);
    }
    int ks2 = c >> 4, lh2 = (c >> 3) & 1, j2 = c & 7;
    float shf = b1[c];
#pragma unroll
    for (int reg = 0; reg < 16; ++reg) {
      int row = (reg & 3) + ((reg >> 2) << 3) + (lhi << 2);
      Bs[ks2][lh2][rbase + row][j2] = f2bf(fmaxf(facc[reg] + shf, 0.f));
    }
  }
  __syncthreads();

  // ---- phase 3: h = leaky0.1(bn(hid @ W2 + b2)) -> global + pooled atomics ----
  {
    floatx16 facc = (floatx16)(0.f);
    const bf16x8* wf = (const bf16x8*)Wf2;
#pragma unroll
    for (int ks = 0; ks < 16; ++ks) {
      bf16x8 a = *(const bf16x8*)&Bs[ks][lhi][rbase + lrow][0];
      bf16x8 bb = wf[((cslab * 16 + ks) << 6) + lane];
      facc = __builtin_amdgcn_mfma_f32_32x32x16_bf16(a, bb, facc, 0, 0, 0);
    }
    float s = bng[c] * rsqrtf(bnv[c] + BN_EPS);
    float shf = b2[c] * s + bnb[c] - bnm[c] * s;
    float run = 0.f;
    int gprev = gsh[rbase + (lhi << 2)];  // first row in this lane's set
#pragma unroll
    for (int reg = 0; reg < 16; ++reg) {
      int row = rbase + (reg & 3) + ((reg >> 2) << 3) + (lhi << 2);  // ascending
      int mrow = m0 + row;
      float v = facc[reg] * s + shf;
      v = (v > 0.f) ? v : 0.1f * v;
      if (mrow < NN) {
        hout[(size_t)mrow * DD + c] = f2bf(v);
      } else {
        v = 0.f;  // padded rows contribute nothing to the pool
      }
      int gg = gsh[row];
      if (gg != gprev) {
        atomicAdd(&t0f[(size_t)gprev * DD + c], run);
        run = 0.f;
        gprev = gg;
      }
      run += v;
    }
    atomicAdd(&t0f[(size_t)gprev * DD + c], run);
  }
}

// ------- fused vn MLP: vn = relu(bn2(relu(bn1((t0f+vn)@W1+b1))@W2+b2)) -------
// gin-style geometry: 512 thr, 32 rows/block, 63 blocks. Re-zeroes its own
// t0f rows (read by same thread before the zero -> no race; block-exclusive).
__global__ __launch_bounds__(512) void k_vn_mlp(
    float* __restrict__ t0f,
    const unsigned short* __restrict__ Wf1, const float* __restrict__ b1,
    const float* __restrict__ bn1g, const float* __restrict__ bn1b,
    const float* __restrict__ bn1m, const float* __restrict__ bn1v,
    const unsigned short* __restrict__ Wf2, const float* __restrict__ b2,
    const float* __restrict__ bn2g, const float* __restrict__ bn2b,
    const float* __restrict__ bn2m, const float* __restrict__ bn2v,
    unsigned short* __restrict__ vnb) {
  __shared__ unsigned short As[16][2][32][8];  // 16 KB
  __shared__ unsigned short Bs[16][2][32][8];  // 16 KB
  int tid = threadIdx.x;
  int m0 = blockIdx.x * 32;
  int r = tid >> 4, q = tid & 15;
  int m = m0 + r;
  int cb = q << 4;
  {
    uint4 wa = make_uint4(0u, 0u, 0u, 0u), wb = wa;
    if (m < NG) {
      float* tp = t0f + (size_t)m * DD + cb;
      float4 a0 = *(const float4*)tp;
      float4 a1 = *(const float4*)(tp + 4);
      float4 a2 = *(const float4*)(tp + 8);
      float4 a3 = *(const float4*)(tp + 12);
      const unsigned short* vp = vnb + (size_t)m * DD + cb;
      uint4 vv0 = *(const uint4*)vp;
      uint4 vv1 = *(const uint4*)(vp + 8);
      wa.x = pack2(a0.x + blo(vv0.x), a0.y + bhi(vv0.x));
      wa.y = pack2(a0.z + blo(vv0.y), a0.w + bhi(vv0.y));
      wa.z = pack2(a1.x + blo(vv0.z), a1.y + bhi(vv0.z));
      wa.w = pack2(a1.z + blo(vv0.w), a1.w + bhi(vv0.w));
      wb.x = pack2(a2.x + blo(vv1.x), a2.y + bhi(vv1.x));
      wb.y = pack2(a2.z + blo(vv1.y), a2.w + bhi(vv1.y));
      wb.z = pack2(a3.x + blo(vv1.z), a3.y + bhi(vv1.z));
      wb.w = pack2(a3.z + blo(vv1.w), a3.w + bhi(vv1.w));
      float4 z = make_float4(0.f, 0.f, 0.f, 0.f);
      *(float4*)tp = z;
      *(float4*)(tp + 4) = z;
      *(float4*)(tp + 8) = z;
      *(float4*)(tp + 12) = z;
    }
    *(uint4*)&As[q][0][r][0] = wa;
    *(uint4*)&As[q][1][r][0] = wb;
  }
  __syncthreads();

  int wave = tid >> 6, lane = tid & 63;
  int lrow = lane & 31, lhi = lane >> 5;
  int c = wave * 32 + lrow;

  // ---- phase 2: t1 = relu(bn1(t @ W1 + b1)) -> Bs ----
  {
    floatx16 facc = (floatx16)(0.f);
    const bf16x8* wf = (const bf16x8*)Wf1;
#pragma unroll
    for (int ks = 0; ks < 16; ++ks) {
      bf16x8 a = *(const bf16x8*)&As[ks][lhi][lrow][0];
      bf16x8 bb = wf[((wave * 16 + ks) << 6) + lane];
      facc = __builtin_amdgcn_mfma_f32_32x32x16_bf16(a, bb, facc, 0, 0, 0);
    }
    float s = bn1g[c] * rsqrtf(bn1v[c] + BN_EPS);
    float shf = b1[c] * s + bn1b[c] - bn1m[c] * s;
    int ks2 = c >> 4, lh2 = (c >> 3) & 1, j2 = c & 7;
#pragma unroll
    for (int reg = 0; reg < 16; ++reg) {
      int row = (reg & 3) + ((reg >> 2) << 3) + (lhi << 2);
      Bs[ks2][lh2][row][j2] = f2bf(fmaxf(facc[reg] * s + shf, 0.f));
    }
  }
  __syncthreads();

  // ---- phase 3: vn = relu(bn2(t1 @ W2 + b2)) -> global ----
  {
    floatx16 facc = (floatx16)(0.f);
    const bf16x8* wf = (const bf16x8*)Wf2;
#pragma unroll
    for (int ks = 0; ks < 16; ++ks) {
      bf16x8 a = *(const bf16x8*)&Bs[ks][lhi][lrow][0];
      bf16x8 bb = wf[((wave * 16 + ks) << 6) + lane];
      facc = __builtin_amdgcn_mfma_f32_32x32x16_bf16(a, bb, facc, 0, 0, 0);
    }
    float s = bn2g[c] * rsqrtf(bn2v[c] + BN_EPS);
    float shf = b2[c] * s + bn2b[c] - bn2m[c] * s;
#pragma unroll
    for (int reg = 0; reg < 16; ++reg) {
      int row = (reg & 3) + ((reg >> 2) << 3) + (lhi << 2);
      int mm = m0 + row;
      if (mm < NG)
        vnb[(size_t)mm * DD + c] = f2bf(fmaxf(facc[reg] * s + shf, 0.f));
    }
  }
}

// ---------------- fused head: out = relu(relu(g@W1+b1)@W2+b2)@W3+b3, all fp32 -------
__global__ __launch_bounds__(256) void k_head(
    const float* __restrict__ X,
    const float* __restrict__ w1, const float* __restrict__ b1,
    const float* __restrict__ w2, const float* __restrict__ b2,
    const float* __restrict__ w3, const float* __restrict__ b3,
    float* __restrict__ out) {
  __shared__ float Xs[32][260];
  __shared__ float Ws[8192];
  __shared__ float H1[32][132];
  __shared__ float H2[32][68];
  __shared__ float W3s[64][12];
  int tid = threadIdx.x;
  int m0 = blockIdx.x * 32;
#pragma unroll
  for (int i = 0; i < 8; ++i) {
    int p = i * 256 + tid;
    int r = p >> 6, c4 = (p & 63) << 2;
    float4 v = make_float4(0.f, 0.f, 0.f, 0.f);
    if (m0 + r < NG) v = *(const float4*)(X + (size_t)(m0 + r) * 256 + c4);
    *(float4*)&Xs[r][c4] = v;
  }
  for (int p = tid; p < 704; p += 256) W3s[p / 11][p % 11] = w3[p];

  int r0 = (tid >> 5) << 2;
  int c0 = (tid & 31) << 2;
  float a1[4][4] = {};
  for (int k0 = 0; k0 < 256; k0 += 64) {
    __syncthreads();
#pragma unroll
    for (int i = 0; i < 8; ++i) {
      int p = i * 256 + tid;
      int r = p >> 5, c4 = (p & 31) << 2;
      *(float4*)&Ws[r * 128 + c4] = *(const float4*)(w1 + (size_t)(k0 + r) * 128 + c4);
    }
    __syncthreads();
#pragma unroll 4
    for (int k = 0; k < 64; ++k) {
      float4 wv = *(float4*)&Ws[k * 128 + c0];
      float xv[4];
#pragma unroll
      for (int i = 0; i < 4; ++i) xv[i] = Xs[r0 + i][k0 + k];
#pragma unroll
      for (int i = 0; i < 4; ++i) {
        a1[i][0] = fmaf(xv[i], wv.x, a1[i][0]);
        a1[i][1] = fmaf(xv[i], wv.y, a1[i][1]);
        a1[i][2] = fmaf(xv[i], wv.z, a1[i][2]);
        a1[i][3] = fmaf(xv[i], wv.w, a1[i][3]);
      }
    }
  }
#pragma unroll
  for (int i = 0; i < 4; ++i) {
    float4 o;
    o.x = fmaxf(a1[i][0] + b1[c0 + 0], 0.f);
    o.y = fmaxf(a1[i][1] + b1[c0 + 1], 0.f);
    o.z = fmaxf(a1[i][2] + b1[c0 + 2], 0.f);
    o.w = fmaxf(a1[i][3] + b1[c0 + 3], 0.f);
    *(float4*)&H1[r0 + i][c0] = o;
  }
  __syncthreads();
#pragma unroll
  for (int i = 0; i < 8; ++i) {
    int p = i * 256 + tid;
    int r = p >> 4, c4 = (p & 15) << 2;
    *(float4*)&Ws[r * 64 + c4] = *(const float4*)(w2 + (size_t)r * 64 + c4);
  }
  __syncthreads();
  int r2 = (tid >> 4) << 1;
  int c2 = (tid & 15) << 2;
  float a2[2][4] = {};
#pragma unroll 4
  for (int k = 0; k < 128; ++k) {
    float4 wv = *(float4*)&Ws[k * 64 + c2];
    float x0 = H1[r2][k], x1 = H1[r2 + 1][k];
    a2[0][0] = fmaf(x0, wv.x, a2[0][0]);
    a2[0][1] = fmaf(x0, wv.y, a2[0][1]);
    a2[0][2] = fmaf(x0, wv.z, a2[0][2]);
    a2[0][3] = fmaf(x0, wv.w, a2[0][3]);
    a2[1][0] = fmaf(x1, wv.x, a2[1][0]);
    a2[1][1] = fmaf(x1, wv.y, a2[1][1]);
    a2[1][2] = fmaf(x1, wv.z, a2[1][2]);
    a2[1][3] = fmaf(x1, wv.w, a2[1][3]);
  }
#pragma unroll
  for (int i = 0; i < 2; ++i) {
    float4 o;
    o.x = fmaxf(a2[i][0] + b2[c2 + 0], 0.f);
    o.y = fmaxf(a2[i][1] + b2[c2 + 1], 0.f);
    o.z = fmaxf(a2[i][2] + b2[c2 + 2], 0.f);
    o.w = fmaxf(a2[i][3] + b2[c2 + 3], 0.f);
    *(float4*)&H2[r2 + i][c2] = o;
  }
  __syncthreads();
  for (int p = tid; p < 352; p += 256) {
    int r = p / 11, c = p - (p / 11) * 11;
    float acc = b3[c];
#pragma unroll 8
    for (int k = 0; k < 64; ++k) acc = fmaf(H2[r][k], W3s[k][c], acc);
    if (m0 + r < NG) out[(size_t)(m0 + r) * 11 + c] = acc;
  }
}

extern "C" void kernel_launch(void* const* d_in, const int* in_sizes, int n_in,
                              void* d_out, int out_size, void* d_ws, size_t ws_size,
                              hipStream_t stream) {
  const float* x      = (const float*)d_in[0];
  const int*   ei     = (const int*)d_in[1];
  const int*   batch  = (const int*)d_in[2];
  const float* node_w = (const float*)d_in[3];
  const float* node_b = (const float*)d_in[4];
  const float* vn_w   = (const float*)d_in[5];
  const float* gin_w1 = (const float*)d_in[6];
  const float* gin_b1 = (const float*)d_in[7];
  const float* gin_w2 = (const float*)d_in[8];
  const float* gin_b2 = (const float*)d_in[9];
  const float* bn_g   = (const float*)d_in[10];
  const float* bn_b   = (const float*)d_in[11];
  const float* bn_m   = (const float*)d_in[12];
  const float* bn_v   = (const float*)d_in[13];
  const float* vn_w1  = (const float*)d_in[14];
  const float* vn_b1  = (const float*)d_in[15];
  const float* vbn1g  = (const float*)d_in[16];
  const float* vbn1b  = (const float*)d_in[17];
  const float* vbn1m  = (const float*)d_in[18];
  const float* vbn1v  = (const float*)d_in[19];
  const float* vn_w2  = (const float*)d_in[20];
  const float* vn_b2  = (const float*)d_in[21];
  const float* vbn2g  = (const float*)d_in[22];
  const float* vbn2b  = (const float*)d_in[23];
  const float* vbn2m  = (const float*)d_in[24];
  const float* vbn2v  = (const float*)d_in[25];
  const float* head_w1 = (const float*)d_in[26];
  const float* head_b1 = (const float*)d_in[27];
  const float* head_w2 = (const float*)d_in[28];
  const float* head_b2 = (const float*)d_in[29];
  const float* head_w3 = (const float*)d_in[30];
  const float* head_b3 = (const float*)d_in[31];

  // ---- workspace layout (~111 MB) ----
  unsigned short* h16   = (unsigned short*)d_ws;          // [NN*DD] ping
  unsigned short* u16   = h16 + (size_t)NN * DD;          // [NN*DD] pong
  unsigned short* vnb   = u16 + (size_t)NN * DD;          // [NG*DD]
  unsigned short* wf1   = vnb + (size_t)NG * DD;          // [5*65536]
  unsigned short* wf2   = wf1 + 5 * 65536;                // [5*65536]
  unsigned short* wfv1  = wf2 + 5 * 65536;                // [4*65536]
  unsigned short* wfv2  = wfv1 + 4 * 65536;               // [4*65536]
  float* t0f   = (float*)(wfv2 + 4 * 65536);              // [NG*DD]
  int2* ssrc2  = (int2*)(t0f + (size_t)NG * DD);          // [NE] (8B aligned)
  int* rowptr  = (int*)(ssrc2 + NE);                      // [NN+1]
  int* cursor  = rowptr + NN + 1;                         // [NN] (zeroed in pack)
  int* bsum    = cursor + NN;                             // [128]
  int* bbase   = bsum + 128;                              // [128]

  const int* src = ei;
  const int* dst = ei + NE;

  const int NB = (NN + 1023) / 1024;  // 98

  // ---- once per launch: weight pack + vn init + zeros + CSR ----
  const int AUXB = (NG * DD + NN + NG * DD + 255) / 256;
  k_pack_all<<<WBLK + AUXB, 256, 0, stream>>>(
      gin_w1, gin_w2, vn_w1, vn_w2, wf1, vn_w, vnb, cursor, t0f);
  k_hist<<<(NE + 255) / 256, 256, 0, stream>>>(dst, cursor);
  k_bsum<<<NB, 1024, 0, stream>>>(cursor, bsum);
  k_scanb<<<1, 128, 0, stream>>>(bsum, bbase, NB);
  k_rowptr<<<NB, 1024, 0, stream>>>(cursor, bbase, rowptr, cursor);
  k_fill_src<<<(NE + 255) / 256, 256, 0, stream>>>(src, dst, batch, cursor, ssrc2);

  unsigned short* hin = h16;
  unsigned short* hout = u16;
  k_node_encode<<<NN / 16, 256, 0, stream>>>(x, node_w, node_b, hin);

  const int GG_NN = (NN + 63) / 64;   // 1563
  const int GM_NG = (NG + 31) / 32;   // 63

  for (int l = 0; l < NL; ++l) {
    // h_out = leaky(bn(relu(((h+vn)[m] + sum (h+vn)[src]) @W1+b1) @W2+b2));
    // pooled sums -> t0f atomics (t0f zeroed by pack_all / previous vn_mlp)
    k_gin_layer<<<GG_NN, 1024, 0, stream>>>(
        hin, vnb, ssrc2, batch, rowptr,
        wf1 + (size_t)l * 65536, gin_b1 + l * DD,
        wf2 + (size_t)l * 65536, gin_b2 + l * DD,
        bn_g + l * DD, bn_b + l * DD, bn_m + l * DD, bn_v + l * DD,
        hout, t0f);
    if (l < NL - 1) {
      // vn = mlp(t0f + vn); also re-zeroes t0f for the next layer
      k_vn_mlp<<<GM_NG, 512, 0, stream>>>(
          t0f,
          wfv1 + (size_t)l * 65536, vn_b1 + l * DD,
          vbn1g + l * DD, vbn1b + l * DD, vbn1m + l * DD, vbn1v + l * DD,
          wfv2 + (size_t)l * 65536, vn_b2 + l * DD,
          vbn2g + l * DD, vbn2b + l * DD, vbn2m + l * DD, vbn2v + l * DD,
          vnb);
    }
    unsigned short* tmp = hin; hin = hout; hout = tmp;
  }
  // head reads the last layer's pooled sums directly (f32, no vn)
  k_head<<<(NG + 31) / 32, 256, 0, stream>>>(
      t0f, head_w1, head_b1, head_w2, head_b2, head_w3, head_b3, (float*)d_out);
}

// Round 9
// 602.396 us; speedup vs baseline: 1.2639x; 1.2639x over previous
//
#include <hip/hip_runtime.h>
#include <hip/hip_bf16.h>

#define NN 100000
#define NE 300000
#define NG 2000
#define DD 256
#define NL 5
#define BN_EPS 1e-5f

typedef __bf16 bf16x8 __attribute__((ext_vector_type(8)));
typedef float floatx16 __attribute__((ext_vector_type(16)));

__device__ inline unsigned short f2bf(float x) {
  unsigned int u = __builtin_bit_cast(unsigned int, x);
  unsigned int r = u + 0x7FFFu + ((u >> 16) & 1u);
  return (unsigned short)(r >> 16);
}
__device__ inline float bf2f(unsigned short u) {
  return __builtin_bit_cast(float, (unsigned int)u << 16);
}
__device__ inline float blo(unsigned int v) {
  return __builtin_bit_cast(float, v << 16);
}
__device__ inline float bhi(unsigned int v) {
  return __builtin_bit_cast(float, v & 0xFFFF0000u);
}
__device__ inline unsigned int pack2(float a, float b) {
  return (unsigned int)f2bf(a) | ((unsigned int)f2bf(b) << 16);
}

// ---- weight pack (coalesced LDS-transpose) + vn init + cursor/t0f zero ----
#define WBLK (18 * 64)
__global__ __launch_bounds__(256) void k_pack_all(
    const float* __restrict__ gw1, const float* __restrict__ gw2,
    const float* __restrict__ vw1, const float* __restrict__ vw2,
    unsigned short* __restrict__ Wf,
    const float* __restrict__ vnw, unsigned short* __restrict__ vnb,
    int* __restrict__ cursor, float* __restrict__ t0f) {
  int bb = blockIdx.x;
  int tid = threadIdx.x;
  if (bb < WBLK) {
    __shared__ float sh[16][65];  // +1 pad: conflict-free column reads
    int m = bb >> 6;        // matrix 0..17
    int tile = bb & 63;
    int kt = tile >> 2;     // 16 k-tiles of 16
    int nt4 = tile & 3;     // 4 n-tiles of 64
    const float* W;
    int mm;
    if (m < 5) { W = gw1; mm = m; }
    else if (m < 10) { W = gw2; mm = m - 5; }
    else if (m < 14) { W = vw1; mm = m - 10; }
    else { W = vw2; mm = m - 14; }
    int k0 = kt * 16, n0 = nt4 * 64;
    int kk = tid >> 4, c4 = (tid & 15) << 2;
    *(float4*)&sh[kk][c4] =
        *(const float4*)(W + (size_t)mm * 65536 + (k0 + kk) * 256 + n0 + c4);
    __syncthreads();
    if (tid < 128) {
      int lh = tid >> 6, nn = tid & 63;
      unsigned short o[8];
#pragma unroll
      for (int j = 0; j < 8; ++j) o[j] = f2bf(sh[lh * 8 + j][nn]);
      int lane = lh * 32 + (nn & 31);
      int ntg = (n0 + nn) >> 5;
      size_t off = (size_t)m * 65536 + ntg * 8192 + kt * 512 + lane * 8;
      *(uint4*)(Wf + off) = *(uint4*)o;
    }
    return;
  }
  int i = (bb - WBLK) * 256 + tid;
  if (i < NG * DD) { vnb[i] = f2bf(vnw[i & (DD - 1)]); return; }
  i -= NG * DD;
  if (i < NN) { cursor[i] = 0; return; }
  i -= NN;
  if (i < NG * DD) t0f[i] = 0.f;
}

// ---------------- CSR build ----------------
__global__ __launch_bounds__(256) void k_hist(const int* __restrict__ dst,
                                              int* __restrict__ cnt) {
  int e = blockIdx.x * 256 + threadIdx.x;
  if (e < NE) atomicAdd(&cnt[dst[e]], 1);
}

__global__ __launch_bounds__(1024) void k_bsum(const int* __restrict__ cnt,
                                               int* __restrict__ bsum) {
  __shared__ int sh[1024];
  int t = threadIdx.x, idx = blockIdx.x * 1024 + t;
  sh[t] = (idx < NN) ? cnt[idx] : 0;
  __syncthreads();
  for (int off = 512; off > 0; off >>= 1) {
    if (t < off) sh[t] += sh[t + off];
    __syncthreads();
  }
  if (t == 0) bsum[blockIdx.x] = sh[0];
}

__global__ __launch_bounds__(128) void k_scanb(const int* __restrict__ bsum,
                                               int* __restrict__ bbase, int nb) {
  __shared__ int sh[128];
  int t = threadIdx.x;
  sh[t] = (t < nb) ? bsum[t] : 0;
  __syncthreads();
  if (t == 0) {
    int run = 0;
    for (int i = 0; i < nb; ++i) { int v = sh[i]; sh[i] = run; run += v; }
  }
  __syncthreads();
  if (t < nb) bbase[t] = sh[t];
}

__global__ __launch_bounds__(1024) void k_rowptr(const int* __restrict__ cnt,
                                                 const int* __restrict__ bbase,
                                                 int* __restrict__ rowptr,
                                                 int* __restrict__ cursor) {
  __shared__ int sh[1024];
  int t = threadIdx.x, idx = blockIdx.x * 1024 + t;
  int v = (idx < NN) ? cnt[idx] : 0;
  sh[t] = v;
  __syncthreads();
  for (int off = 1; off < 1024; off <<= 1) {
    int add = (t >= off) ? sh[t - off] : 0;
    __syncthreads();
    sh[t] += add;
    __syncthreads();
  }
  if (idx < NN) {
    int excl = sh[t] - v + bbase[blockIdx.x];
    rowptr[idx] = excl;
    cursor[idx] = excl;
  }
  if (blockIdx.x == 0 && t == 0) rowptr[NN] = NE;
}

// writes (src, batch[src]) so the fused gather has no dependent load chain
__global__ __launch_bounds__(256) void k_fill_src(const int* __restrict__ src,
                                                  const int* __restrict__ dst,
                                                  const int* __restrict__ batch,
                                                  int* __restrict__ cursor,
                                                  int2* __restrict__ ssrc2) {
  int e = blockIdx.x * 256 + threadIdx.x;
  if (e >= NE) return;
  int s = src[e];
  int pos = atomicAdd(&cursor[dst[e]], 1);
  ssrc2[pos] = make_int2(s, batch[s]);
}

// ---------------- node encode -> bf16 (16 nodes/block, w in LDS) ----------------
__global__ __launch_bounds__(256) void k_node_encode(
    const float* __restrict__ x, const float* __restrict__ w,
    const float* __restrict__ b, unsigned short* __restrict__ h16) {
  __shared__ float ws[20][256];
  __shared__ float xr[16][20];
  int tid = threadIdx.x;
  int n0 = blockIdx.x * 16;
  for (int p = tid; p < 20 * 64; p += 256) {
    int k = p >> 6, c4 = (p & 63) << 2;
    *(float4*)&ws[k][c4] = *(const float4*)(w + k * 256 + c4);
  }
  for (int p = tid; p < 320; p += 256) {
    int nn = p / 20, k = p - nn * 20;
    xr[nn][k] = x[(size_t)(n0 + nn) * 20 + k];
  }
  __syncthreads();
  int ln = tid >> 6, c4 = (tid & 63) << 2;
  float4 bv = *(const float4*)(b + c4);
  float a[4][4];
#pragma unroll
  for (int nn = 0; nn < 4; ++nn) {
    a[nn][0] = bv.x; a[nn][1] = bv.y; a[nn][2] = bv.z; a[nn][3] = bv.w;
  }
#pragma unroll
  for (int k = 0; k < 20; ++k) {
    float4 wv = *(float4*)&ws[k][c4];
#pragma unroll
    for (int nn = 0; nn < 4; ++nn) {
      float xv = xr[ln * 4 + nn][k];
      a[nn][0] = fmaf(xv, wv.x, a[nn][0]);
      a[nn][1] = fmaf(xv, wv.y, a[nn][1]);
      a[nn][2] = fmaf(xv, wv.z, a[nn][2]);
      a[nn][3] = fmaf(xv, wv.w, a[nn][3]);
    }
  }
#pragma unroll
  for (int nn = 0; nn < 4; ++nn) {
    int n = n0 + ln * 4 + nn;
    *(ushort4*)(h16 + (size_t)n * DD + c4) =
        make_ushort4(f2bf(a[nn][0]), f2bf(a[nn][1]), f2bf(a[nn][2]), f2bf(a[nn][3]));
  }
}

// ---------------- fused GIN layer (512 threads, 32 rows/block) ----------------
// The R6 form EXACTLY - best of 7 measured variants (82.4us):
//   16 thr/row x 16 cols, plain compiler-scheduled edge loop.
//   NO manual prefetch (R1/R2: -20us), NO LDS swizzle (R4: -10us),
//   NO x2 unroll (R7: neutral, +8 VGPR), NO 64-row block (R8: -32us,
//   barrier-tail + occupancy loss). vn fused in gather (R6: -55us net),
//   atomic pool epilogue (R5: -44us net).
__global__ __launch_bounds__(512) void k_gin_layer(
    const unsigned short* __restrict__ hin, const unsigned short* __restrict__ vnb,
    const int2* __restrict__ ssrc2, const int* __restrict__ batch,
    const int* __restrict__ rowptr,
    const unsigned short* __restrict__ Wf1, const float* __restrict__ b1,
    const unsigned short* __restrict__ Wf2, const float* __restrict__ b2,
    const float* __restrict__ bng, const float* __restrict__ bnb,
    const float* __restrict__ bnm, const float* __restrict__ bnv,
    unsigned short* __restrict__ hout, float* __restrict__ t0f) {
  __shared__ unsigned short As[16][2][32][8];  // 16 KB z fragments
  __shared__ unsigned short Bs[16][2][32][8];  // 16 KB hid fragments
  __shared__ int gsh[32];
  int tid = threadIdx.x;
  int m0 = blockIdx.x * 32;      // 3125 * 32 = 100000 exactly
  int r = tid >> 4, q = tid & 15;  // row 0..31, col chunk 0..15
  int m = m0 + r;
  int cb = q << 4;               // col base (16 cols per thread)
  if (tid < 32) gsh[tid] = batch[m0 + tid];
  {
    float acc[16];
#define SET8(off, H, V)                                \
  acc[(off) + 0] = blo((H).x) + blo((V).x);            \
  acc[(off) + 1] = bhi((H).x) + bhi((V).x);            \
  acc[(off) + 2] = blo((H).y) + blo((V).y);            \
  acc[(off) + 3] = bhi((H).y) + bhi((V).y);            \
  acc[(off) + 4] = blo((H).z) + blo((V).z);            \
  acc[(off) + 5] = bhi((H).z) + bhi((V).z);            \
  acc[(off) + 6] = blo((H).w) + blo((V).w);            \
  acc[(off) + 7] = bhi((H).w) + bhi((V).w);
#define ACC8(off, H, V)                                \
  acc[(off) + 0] += blo((H).x) + blo((V).x);           \
  acc[(off) + 1] += bhi((H).x) + bhi((V).x);           \
  acc[(off) + 2] += blo((H).y) + blo((V).y);           \
  acc[(off) + 3] += bhi((H).y) + bhi((V).y);           \
  acc[(off) + 4] += blo((H).z) + blo((V).z);           \
  acc[(off) + 5] += bhi((H).z) + bhi((V).z);           \
  acc[(off) + 6] += blo((H).w) + blo((V).w);           \
  acc[(off) + 7] += bhi((H).w) + bhi((V).w);
    {
      int bm = batch[m];
      const unsigned short* hp = hin + (size_t)m * DD + cb;
      const unsigned short* vp = vnb + (size_t)bm * DD + cb;
      uint4 h0 = *(const uint4*)hp, h1 = *(const uint4*)(hp + 8);
      uint4 v0 = *(const uint4*)vp, v1 = *(const uint4*)(vp + 8);
      SET8(0, h0, v0) SET8(8, h1, v1)
    }
    int b = rowptr[m], e = rowptr[m + 1];
    for (int t = b; t < e; ++t) {
      int2 sp = ssrc2[t];
      const unsigned short* hp = hin + (size_t)sp.x * DD + cb;
      const unsigned short* vp = vnb + (size_t)sp.y * DD + cb;
      uint4 h0 = *(const uint4*)hp, h1 = *(const uint4*)(hp + 8);
      uint4 v0 = *(const uint4*)vp, v1 = *(const uint4*)(vp + 8);
      ACC8(0, h0, v0) ACC8(8, h1, v1)
    }
#undef SET8
#undef ACC8
    // cols cb+i*8+j -> fragment [ks=q][lh=i][row=r][j]
#pragma unroll
    for (int i = 0; i < 2; ++i) {
      uint4 o;
      o.x = pack2(acc[i * 8 + 0], acc[i * 8 + 1]);
      o.y = pack2(acc[i * 8 + 2], acc[i * 8 + 3]);
      o.z = pack2(acc[i * 8 + 4], acc[i * 8 + 5]);
      o.w = pack2(acc[i * 8 + 6], acc[i * 8 + 7]);
      *(uint4*)&As[q][i][r][0] = o;
    }
  }
  __syncthreads();

  int wave = tid >> 6, lane = tid & 63;  // wave in [0,8)
  int lrow = lane & 31, lhi = lane >> 5;
  int c = wave * 32 + lrow;

  // ---- phase 2: hid = relu(z @ W1 + b1) -> Bs ----
  {
    floatx16 facc = (floatx16)(0.f);
    const bf16x8* wf = (const bf16x8*)Wf1;
#pragma unroll
    for (int ks = 0; ks < 16; ++ks) {
      bf16x8 a = *(const bf16x8*)&As[ks][lhi][lrow][0];
      bf16x8 bb = wf[((wave * 16 + ks) << 6) + lane];
      facc = __builtin_amdgcn_mfma_f32_32x32x16_bf16(a, bb, facc, 0, 0, 0);
    }
    int ks2 = c >> 4, lh2 = (c >> 3) & 1, j2 = c & 7;
    float shf = b1[c];
#pragma unroll
    for (int reg = 0; reg < 16; ++reg) {
      int row = (reg & 3) + ((reg >> 2) << 3) + (lhi << 2);
      Bs[ks2][lh2][row][j2] = f2bf(fmaxf(facc[reg] + shf, 0.f));
    }
  }
  __syncthreads();

  // ---- phase 3: h = leaky0.1(bn(hid @ W2 + b2)) -> global + pooled atomics ----
  {
    floatx16 facc = (floatx16)(0.f);
    const bf16x8* wf = (const bf16x8*)Wf2;
#pragma unroll
    for (int ks = 0; ks < 16; ++ks) {
      bf16x8 a = *(const bf16x8*)&Bs[ks][lhi][lrow][0];
      bf16x8 bb = wf[((wave * 16 + ks) << 6) + lane];
      facc = __builtin_amdgcn_mfma_f32_32x32x16_bf16(a, bb, facc, 0, 0, 0);
    }
    float s = bng[c] * rsqrtf(bnv[c] + BN_EPS);
    float shf = b2[c] * s + bnb[c] - bnm[c] * s;
    float run = 0.f;
    int gprev = gsh[lhi << 2];  // first row in this lane half's ascending set
#pragma unroll
    for (int reg = 0; reg < 16; ++reg) {
      int row = (reg & 3) + ((reg >> 2) << 3) + (lhi << 2);  // ascending
      float v = facc[reg] * s + shf;
      v = (v > 0.f) ? v : 0.1f * v;
      hout[(size_t)(m0 + row) * DD + c] = f2bf(v);
      int gg = gsh[row];
      if (gg != gprev) {
        atomicAdd(&t0f[(size_t)gprev * DD + c], run);
        run = 0.f;
        gprev = gg;
      }
      run += v;
    }
    atomicAdd(&t0f[(size_t)gprev * DD + c], run);
  }
}

// ------- fused vn MLP: vn = relu(bn2(relu(bn1((t0f+vn)@W1+b1))@W2+b2)) -------
// gin-style geometry: 512 thr, 32 rows/block, 63 blocks. Re-zeroes its own
// t0f rows (read by same thread before the zero -> no race; block-exclusive).
__global__ __launch_bounds__(512) void k_vn_mlp(
    float* __restrict__ t0f,
    const unsigned short* __restrict__ Wf1, const float* __restrict__ b1,
    const float* __restrict__ bn1g, const float* __restrict__ bn1b,
    const float* __restrict__ bn1m, const float* __restrict__ bn1v,
    const unsigned short* __restrict__ Wf2, const float* __restrict__ b2,
    const float* __restrict__ bn2g, const float* __restrict__ bn2b,
    const float* __restrict__ bn2m, const float* __restrict__ bn2v,
    unsigned short* __restrict__ vnb) {
  __shared__ unsigned short As[16][2][32][8];  // 16 KB
  __shared__ unsigned short Bs[16][2][32][8];  // 16 KB
  int tid = threadIdx.x;
  int m0 = blockIdx.x * 32;
  int r = tid >> 4, q = tid & 15;
  int m = m0 + r;
  int cb = q << 4;
  {
    uint4 wa = make_uint4(0u, 0u, 0u, 0u), wb = wa;
    if (m < NG) {
      float* tp = t0f + (size_t)m * DD + cb;
      float4 a0 = *(const float4*)tp;
      float4 a1 = *(const float4*)(tp + 4);
      float4 a2 = *(const float4*)(tp + 8);
      float4 a3 = *(const float4*)(tp + 12);
      const unsigned short* vp = vnb + (size_t)m * DD + cb;
      uint4 vv0 = *(const uint4*)vp;
      uint4 vv1 = *(const uint4*)(vp + 8);
      wa.x = pack2(a0.x + blo(vv0.x), a0.y + bhi(vv0.x));
      wa.y = pack2(a0.z + blo(vv0.y), a0.w + bhi(vv0.y));
      wa.z = pack2(a1.x + blo(vv0.z), a1.y + bhi(vv0.z));
      wa.w = pack2(a1.z + blo(vv0.w), a1.w + bhi(vv0.w));
      wb.x = pack2(a2.x + blo(vv1.x), a2.y + bhi(vv1.x));
      wb.y = pack2(a2.z + blo(vv1.y), a2.w + bhi(vv1.y));
      wb.z = pack2(a3.x + blo(vv1.z), a3.y + bhi(vv1.z));
      wb.w = pack2(a3.z + blo(vv1.w), a3.w + bhi(vv1.w));
      float4 z = make_float4(0.f, 0.f, 0.f, 0.f);
      *(float4*)tp = z;
      *(float4*)(tp + 4) = z;
      *(float4*)(tp + 8) = z;
      *(float4*)(tp + 12) = z;
    }
    *(uint4*)&As[q][0][r][0] = wa;
    *(uint4*)&As[q][1][r][0] = wb;
  }
  __syncthreads();

  int wave = tid >> 6, lane = tid & 63;
  int lrow = lane & 31, lhi = lane >> 5;
  int c = wave * 32 + lrow;

  // ---- phase 2: t1 = relu(bn1(t @ W1 + b1)) -> Bs ----
  {
    floatx16 facc = (floatx16)(0.f);
    const bf16x8* wf = (const bf16x8*)Wf1;
#pragma unroll
    for (int ks = 0; ks < 16; ++ks) {
      bf16x8 a = *(const bf16x8*)&As[ks][lhi][lrow][0];
      bf16x8 bb = wf[((wave * 16 + ks) << 6) + lane];
      facc = __builtin_amdgcn_mfma_f32_32x32x16_bf16(a, bb, facc, 0, 0, 0);
    }
    float s = bn1g[c] * rsqrtf(bn1v[c] + BN_EPS);
    float shf = b1[c] * s + bn1b[c] - bn1m[c] * s;
    int ks2 = c >> 4, lh2 = (c >> 3) & 1, j2 = c & 7;
#pragma unroll
    for (int reg = 0; reg < 16; ++reg) {
      int row = (reg & 3) + ((reg >> 2) << 3) + (lhi << 2);
      Bs[ks2][lh2][row][j2] = f2bf(fmaxf(facc[reg] * s + shf, 0.f));
    }
  }
  __syncthreads();

  // ---- phase 3: vn = relu(bn2(t1 @ W2 + b2)) -> global ----
  {
    floatx16 facc = (floatx16)(0.f);
    const bf16x8* wf = (const bf16x8*)Wf2;
#pragma unroll
    for (int ks = 0; ks < 16; ++ks) {
      bf16x8 a = *(const bf16x8*)&Bs[ks][lhi][lrow][0];
      bf16x8 bb = wf[((wave * 16 + ks) << 6) + lane];
      facc = __builtin_amdgcn_mfma_f32_32x32x16_bf16(a, bb, facc, 0, 0, 0);
    }
    float s = bn2g[c] * rsqrtf(bn2v[c] + BN_EPS);
    float shf = b2[c] * s + bn2b[c] - bn2m[c] * s;
#pragma unroll
    for (int reg = 0; reg < 16; ++reg) {
      int row = (reg & 3) + ((reg >> 2) << 3) + (lhi << 2);
      int mm = m0 + row;
      if (mm < NG)
        vnb[(size_t)mm * DD + c] = f2bf(fmaxf(facc[reg] * s + shf, 0.f));
    }
  }
}

// ---------------- fused head: out = relu(relu(g@W1+b1)@W2+b2)@W3+b3, all fp32 -------
__global__ __launch_bounds__(256) void k_head(
    const float* __restrict__ X,
    const float* __restrict__ w1, const float* __restrict__ b1,
    const float* __restrict__ w2, const float* __restrict__ b2,
    const float* __restrict__ w3, const float* __restrict__ b3,
    float* __restrict__ out) {
  __shared__ float Xs[32][260];
  __shared__ float Ws[8192];
  __shared__ float H1[32][132];
  __shared__ float H2[32][68];
  __shared__ float W3s[64][12];
  int tid = threadIdx.x;
  int m0 = blockIdx.x * 32;
#pragma unroll
  for (int i = 0; i < 8; ++i) {
    int p = i * 256 + tid;
    int r = p >> 6, c4 = (p & 63) << 2;
    float4 v = make_float4(0.f, 0.f, 0.f, 0.f);
    if (m0 + r < NG) v = *(const float4*)(X + (size_t)(m0 + r) * 256 + c4);
    *(float4*)&Xs[r][c4] = v;
  }
  for (int p = tid; p < 704; p += 256) W3s[p / 11][p % 11] = w3[p];

  int r0 = (tid >> 5) << 2;
  int c0 = (tid & 31) << 2;
  float a1[4][4] = {};
  for (int k0 = 0; k0 < 256; k0 += 64) {
    __syncthreads();
#pragma unroll
    for (int i = 0; i < 8; ++i) {
      int p = i * 256 + tid;
      int r = p >> 5, c4 = (p & 31) << 2;
      *(float4*)&Ws[r * 128 + c4] = *(const float4*)(w1 + (size_t)(k0 + r) * 128 + c4);
    }
    __syncthreads();
#pragma unroll 4
    for (int k = 0; k < 64; ++k) {
      float4 wv = *(float4*)&Ws[k * 128 + c0];
      float xv[4];
#pragma unroll
      for (int i = 0; i < 4; ++i) xv[i] = Xs[r0 + i][k0 + k];
#pragma unroll
      for (int i = 0; i < 4; ++i) {
        a1[i][0] = fmaf(xv[i], wv.x, a1[i][0]);
        a1[i][1] = fmaf(xv[i], wv.y, a1[i][1]);
        a1[i][2] = fmaf(xv[i], wv.z, a1[i][2]);
        a1[i][3] = fmaf(xv[i], wv.w, a1[i][3]);
      }
    }
  }
#pragma unroll
  for (int i = 0; i < 4; ++i) {
    float4 o;
    o.x = fmaxf(a1[i][0] + b1[c0 + 0], 0.f);
    o.y = fmaxf(a1[i][1] + b1[c0 + 1], 0.f);
    o.z = fmaxf(a1[i][2] + b1[c0 + 2], 0.f);
    o.w = fmaxf(a1[i][3] + b1[c0 + 3], 0.f);
    *(float4*)&H1[r0 + i][c0] = o;
  }
  __syncthreads();
#pragma unroll
  for (int i = 0; i < 8; ++i) {
    int p = i * 256 + tid;
    int r = p >> 4, c4 = (p & 15) << 2;
    *(float4*)&Ws[r * 64 + c4] = *(const float4*)(w2 + (size_t)r * 64 + c4);
  }
  __syncthreads();
  int r2 = (tid >> 4) << 1;
  int c2 = (tid & 15) << 2;
  float a2[2][4] = {};
#pragma unroll 4
  for (int k = 0; k < 128; ++k) {
    float4 wv = *(float4*)&Ws[k * 64 + c2];
    float x0 = H1[r2][k], x1 = H1[r2 + 1][k];
    a2[0][0] = fmaf(x0, wv.x, a2[0][0]);
    a2[0][1] = fmaf(x0, wv.y, a2[0][1]);
    a2[0][2] = fmaf(x0, wv.z, a2[0][2]);
    a2[0][3] = fmaf(x0, wv.w, a2[0][3]);
    a2[1][0] = fmaf(x1, wv.x, a2[1][0]);
    a2[1][1] = fmaf(x1, wv.y, a2[1][1]);
    a2[1][2] = fmaf(x1, wv.z, a2[1][2]);
    a2[1][3] = fmaf(x1, wv.w, a2[1][3]);
  }
#pragma unroll
  for (int i = 0; i < 2; ++i) {
    float4 o;
    o.x = fmaxf(a2[i][0] + b2[c2 + 0], 0.f);
    o.y = fmaxf(a2[i][1] + b2[c2 + 1], 0.f);
    o.z = fmaxf(a2[i][2] + b2[c2 + 2], 0.f);
    o.w = fmaxf(a2[i][3] + b2[c2 + 3], 0.f);
    *(float4*)&H2[r2 + i][c2] = o;
  }
  __syncthreads();
  for (int p = tid; p < 352; p += 256) {
    int r = p / 11, c = p - (p / 11) * 11;
    float acc = b3[c];
#pragma unroll 8
    for (int k = 0; k < 64; ++k) acc = fmaf(H2[r][k], W3s[k][c], acc);
    if (m0 + r < NG) out[(size_t)(m0 + r) * 11 + c] = acc;
  }
}

extern "C" void kernel_launch(void* const* d_in, const int* in_sizes, int n_in,
                              void* d_out, int out_size, void* d_ws, size_t ws_size,
                              hipStream_t stream) {
  const float* x      = (const float*)d_in[0];
  const int*   ei     = (const int*)d_in[1];
  const int*   batch  = (const int*)d_in[2];
  const float* node_w = (const float*)d_in[3];
  const float* node_b = (const float*)d_in[4];
  const float* vn_w   = (const float*)d_in[5];
  const float* gin_w1 = (const float*)d_in[6];
  const float* gin_b1 = (const float*)d_in[7];
  const float* gin_w2 = (const float*)d_in[8];
  const float* gin_b2 = (const float*)d_in[9];
  const float* bn_g   = (const float*)d_in[10];
  const float* bn_b   = (const float*)d_in[11];
  const float* bn_m   = (const float*)d_in[12];
  const float* bn_v   = (const float*)d_in[13];
  const float* vn_w1  = (const float*)d_in[14];
  const float* vn_b1  = (const float*)d_in[15];
  const float* vbn1g  = (const float*)d_in[16];
  const float* vbn1b  = (const float*)d_in[17];
  const float* vbn1m  = (const float*)d_in[18];
  const float* vbn1v  = (const float*)d_in[19];
  const float* vn_w2  = (const float*)d_in[20];
  const float* vn_b2  = (const float*)d_in[21];
  const float* vbn2g  = (const float*)d_in[22];
  const float* vbn2b  = (const float*)d_in[23];
  const float* vbn2m  = (const float*)d_in[24];
  const float* vbn2v  = (const float*)d_in[25];
  const float* head_w1 = (const float*)d_in[26];
  const float* head_b1 = (const float*)d_in[27];
  const float* head_w2 = (const float*)d_in[28];
  const float* head_b2 = (const float*)d_in[29];
  const float* head_w3 = (const float*)d_in[30];
  const float* head_b3 = (const float*)d_in[31];

  // ---- workspace layout (~111 MB) ----
  unsigned short* h16   = (unsigned short*)d_ws;          // [NN*DD] ping
  unsigned short* u16   = h16 + (size_t)NN * DD;          // [NN*DD] pong
  unsigned short* vnb   = u16 + (size_t)NN * DD;          // [NG*DD]
  unsigned short* wf1   = vnb + (size_t)NG * DD;          // [5*65536]
  unsigned short* wf2   = wf1 + 5 * 65536;                // [5*65536]
  unsigned short* wfv1  = wf2 + 5 * 65536;                // [4*65536]
  unsigned short* wfv2  = wfv1 + 4 * 65536;               // [4*65536]
  float* t0f   = (float*)(wfv2 + 4 * 65536);              // [NG*DD]
  int2* ssrc2  = (int2*)(t0f + (size_t)NG * DD);          // [NE] (8B aligned)
  int* rowptr  = (int*)(ssrc2 + NE);                      // [NN+1]
  int* cursor  = rowptr + NN + 1;                         // [NN] (zeroed in pack)
  int* bsum    = cursor + NN;                             // [128]
  int* bbase   = bsum + 128;                              // [128]

  const int* src = ei;
  const int* dst = ei + NE;

  const int NB = (NN + 1023) / 1024;  // 98

  // ---- once per launch: weight pack + vn init + zeros + CSR ----
  const int AUXB = (NG * DD + NN + NG * DD + 255) / 256;
  k_pack_all<<<WBLK + AUXB, 256, 0, stream>>>(
      gin_w1, gin_w2, vn_w1, vn_w2, wf1, vn_w, vnb, cursor, t0f);
  k_hist<<<(NE + 255) / 256, 256, 0, stream>>>(dst, cursor);
  k_bsum<<<NB, 1024, 0, stream>>>(cursor, bsum);
  k_scanb<<<1, 128, 0, stream>>>(bsum, bbase, NB);
  k_rowptr<<<NB, 1024, 0, stream>>>(cursor, bbase, rowptr, cursor);
  k_fill_src<<<(NE + 255) / 256, 256, 0, stream>>>(src, dst, batch, cursor, ssrc2);

  unsigned short* hin = h16;
  unsigned short* hout = u16;
  k_node_encode<<<NN / 16, 256, 0, stream>>>(x, node_w, node_b, hin);

  const int GG_NN = NN / 32;          // 3125
  const int GM_NG = (NG + 31) / 32;   // 63

  for (int l = 0; l < NL; ++l) {
    // h_out = leaky(bn(relu(((h+vn)[m] + sum (h+vn)[src]) @W1+b1) @W2+b2));
    // pooled sums -> t0f atomics (t0f zeroed by pack_all / previous vn_mlp)
    k_gin_layer<<<GG_NN, 512, 0, stream>>>(
        hin, vnb, ssrc2, batch, rowptr,
        wf1 + (size_t)l * 65536, gin_b1 + l * DD,
        wf2 + (size_t)l * 65536, gin_b2 + l * DD,
        bn_g + l * DD, bn_b + l * DD, bn_m + l * DD, bn_v + l * DD,
        hout, t0f);
    if (l < NL - 1) {
      // vn = mlp(t0f + vn); also re-zeroes t0f for the next layer
      k_vn_mlp<<<GM_NG, 512, 0, stream>>>(
          t0f,
          wfv1 + (size_t)l * 65536, vn_b1 + l * DD,
          vbn1g + l * DD, vbn1b + l * DD, vbn1m + l * DD, vbn1v + l * DD,
          wfv2 + (size_t)l * 65536, vn_b2 + l * DD,
          vbn2g + l * DD, vbn2b + l * DD, vbn2m + l * DD, vbn2v + l * DD,
          vnb);
    }
    unsigned short* tmp = hin; hin = hout; hout = tmp;
  }
  // head reads the last layer's pooled sums directly (f32, no vn)
  k_head<<<(NG + 31) / 32, 256, 0, stream>>>(
      t0f, head_w1, head_b1, head_w2, head_b2, head_w3, head_b3, (float*)d_out);
}

// Round 10
// 584.294 us; speedup vs baseline: 1.3030x; 1.0310x over previous
//
#include <hip/hip_runtime.h>
#include <hip/hip_bf16.h>

#define NN 100000
#define NE 300000
#define NG 2000
#define DD 256
#define NL 5
#define BN_EPS 1e-5f
#define DEGMAX 32   // P(any node degree >= 32 | 300K uniform edges) ~ 1e-17

typedef __bf16 bf16x8 __attribute__((ext_vector_type(8)));
typedef float floatx16 __attribute__((ext_vector_type(16)));

__device__ inline unsigned short f2bf(float x) {
  unsigned int u = __builtin_bit_cast(unsigned int, x);
  unsigned int r = u + 0x7FFFu + ((u >> 16) & 1u);
  return (unsigned short)(r >> 16);
}
__device__ inline float bf2f(unsigned short u) {
  return __builtin_bit_cast(float, (unsigned int)u << 16);
}
__device__ inline float blo(unsigned int v) {
  return __builtin_bit_cast(float, v << 16);
}
__device__ inline float bhi(unsigned int v) {
  return __builtin_bit_cast(float, v & 0xFFFF0000u);
}
__device__ inline unsigned int pack2(float a, float b) {
  return (unsigned int)f2bf(a) | ((unsigned int)f2bf(b) << 16);
}

// ---- weight pack (coalesced LDS-transpose) + vn init + cnt/t0f zero ----
#define WBLK (18 * 64)
__global__ __launch_bounds__(256) void k_pack_all(
    const float* __restrict__ gw1, const float* __restrict__ gw2,
    const float* __restrict__ vw1, const float* __restrict__ vw2,
    unsigned short* __restrict__ Wf,
    const float* __restrict__ vnw, unsigned short* __restrict__ vnb,
    int* __restrict__ cnt, float* __restrict__ t0f) {
  int bb = blockIdx.x;
  int tid = threadIdx.x;
  if (bb < WBLK) {
    __shared__ float sh[16][65];  // +1 pad: conflict-free column reads
    int m = bb >> 6;        // matrix 0..17
    int tile = bb & 63;
    int kt = tile >> 2;     // 16 k-tiles of 16
    int nt4 = tile & 3;     // 4 n-tiles of 64
    const float* W;
    int mm;
    if (m < 5) { W = gw1; mm = m; }
    else if (m < 10) { W = gw2; mm = m - 5; }
    else if (m < 14) { W = vw1; mm = m - 10; }
    else { W = vw2; mm = m - 14; }
    int k0 = kt * 16, n0 = nt4 * 64;
    int kk = tid >> 4, c4 = (tid & 15) << 2;
    *(float4*)&sh[kk][c4] =
        *(const float4*)(W + (size_t)mm * 65536 + (k0 + kk) * 256 + n0 + c4);
    __syncthreads();
    if (tid < 128) {
      int lh = tid >> 6, nn = tid & 63;
      unsigned short o[8];
#pragma unroll
      for (int j = 0; j < 8; ++j) o[j] = f2bf(sh[lh * 8 + j][nn]);
      int lane = lh * 32 + (nn & 31);
      int ntg = (n0 + nn) >> 5;
      size_t off = (size_t)m * 65536 + ntg * 8192 + kt * 512 + lane * 8;
      *(uint4*)(Wf + off) = *(uint4*)o;
    }
    return;
  }
  int i = (bb - WBLK) * 256 + tid;
  if (i < NG * DD) { vnb[i] = f2bf(vnw[i & (DD - 1)]); return; }
  i -= NG * DD;
  if (i < NN) { cnt[i] = 0; return; }
  i -= NN;
  if (i < NG * DD) t0f[i] = 0.f;
}

// ---- padded edge table build: ONE dispatch replaces the 5-kernel CSR chain ----
// sspk[d*32+pos] = (batch[src]<<17) | src  (src<2^17, batch<2^11 -> 28 bits)
__global__ __launch_bounds__(256) void k_fill_src(const int* __restrict__ src,
                                                  const int* __restrict__ dst,
                                                  const int* __restrict__ batch,
                                                  int* __restrict__ cnt,
                                                  int* __restrict__ sspk) {
  int e = blockIdx.x * 256 + threadIdx.x;
  if (e >= NE) return;
  int s = src[e];
  int g = batch[s];
  int d = dst[e];
  int pos = atomicAdd(&cnt[d], 1);
  if (pos < DEGMAX) sspk[d * DEGMAX + pos] = (g << 17) | s;
}

// ---------------- node encode -> bf16 (16 nodes/block, w in LDS) ----------------
__global__ __launch_bounds__(256) void k_node_encode(
    const float* __restrict__ x, const float* __restrict__ w,
    const float* __restrict__ b, unsigned short* __restrict__ h16) {
  __shared__ float ws[20][256];
  __shared__ float xr[16][20];
  int tid = threadIdx.x;
  int n0 = blockIdx.x * 16;
  for (int p = tid; p < 20 * 64; p += 256) {
    int k = p >> 6, c4 = (p & 63) << 2;
    *(float4*)&ws[k][c4] = *(const float4*)(w + k * 256 + c4);
  }
  for (int p = tid; p < 320; p += 256) {
    int nn = p / 20, k = p - nn * 20;
    xr[nn][k] = x[(size_t)(n0 + nn) * 20 + k];
  }
  __syncthreads();
  int ln = tid >> 6, c4 = (tid & 63) << 2;
  float4 bv = *(const float4*)(b + c4);
  float a[4][4];
#pragma unroll
  for (int nn = 0; nn < 4; ++nn) {
    a[nn][0] = bv.x; a[nn][1] = bv.y; a[nn][2] = bv.z; a[nn][3] = bv.w;
  }
#pragma unroll
  for (int k = 0; k < 20; ++k) {
    float4 wv = *(float4*)&ws[k][c4];
#pragma unroll
    for (int nn = 0; nn < 4; ++nn) {
      float xv = xr[ln * 4 + nn][k];
      a[nn][0] = fmaf(xv, wv.x, a[nn][0]);
      a[nn][1] = fmaf(xv, wv.y, a[nn][1]);
      a[nn][2] = fmaf(xv, wv.z, a[nn][2]);
      a[nn][3] = fmaf(xv, wv.w, a[nn][3]);
    }
  }
#pragma unroll
  for (int nn = 0; nn < 4; ++nn) {
    int n = n0 + ln * 4 + nn;
    *(ushort4*)(h16 + (size_t)n * DD + c4) =
        make_ushort4(f2bf(a[nn][0]), f2bf(a[nn][1]), f2bf(a[nn][2]), f2bf(a[nn][3]));
  }
}

// ---------------- fused GIN layer (512 threads, 32 rows/block) ----------------
// The R6/R9 form - best of 8 measured variants (82.4us):
//   16 thr/row x 16 cols, plain compiler-scheduled edge loop.
//   NO manual prefetch (R1/R2: -20us), NO LDS swizzle (R4: -10us),
//   NO x2 unroll (R7: neutral), NO 64-row block (R8: -32us).
//   vn fused in gather (R6: -55us net), atomic pool epilogue (R5: -44us net).
// Edge list is the DEGMAX-padded table: cnt[m] entries at sspk[m*32+..],
// each packed (batch<<17)|src (decode = 2 VALU ops).
__global__ __launch_bounds__(512) void k_gin_layer(
    const unsigned short* __restrict__ hin, const unsigned short* __restrict__ vnb,
    const int* __restrict__ sspk, const int* __restrict__ cnt,
    const int* __restrict__ batch,
    const unsigned short* __restrict__ Wf1, const float* __restrict__ b1,
    const unsigned short* __restrict__ Wf2, const float* __restrict__ b2,
    const float* __restrict__ bng, const float* __restrict__ bnb,
    const float* __restrict__ bnm, const float* __restrict__ bnv,
    unsigned short* __restrict__ hout, float* __restrict__ t0f) {
  __shared__ unsigned short As[16][2][32][8];  // 16 KB z fragments
  __shared__ unsigned short Bs[16][2][32][8];  // 16 KB hid fragments
  __shared__ int gsh[32];
  int tid = threadIdx.x;
  int m0 = blockIdx.x * 32;      // 3125 * 32 = 100000 exactly
  int r = tid >> 4, q = tid & 15;  // row 0..31, col chunk 0..15
  int m = m0 + r;
  int cb = q << 4;               // col base (16 cols per thread)
  if (tid < 32) gsh[tid] = batch[m0 + tid];
  {
    float acc[16];
#define SET8(off, H, V)                                \
  acc[(off) + 0] = blo((H).x) + blo((V).x);            \
  acc[(off) + 1] = bhi((H).x) + bhi((V).x);            \
  acc[(off) + 2] = blo((H).y) + blo((V).y);            \
  acc[(off) + 3] = bhi((H).y) + bhi((V).y);            \
  acc[(off) + 4] = blo((H).z) + blo((V).z);            \
  acc[(off) + 5] = bhi((H).z) + bhi((V).z);            \
  acc[(off) + 6] = blo((H).w) + blo((V).w);            \
  acc[(off) + 7] = bhi((H).w) + bhi((V).w);
#define ACC8(off, H, V)                                \
  acc[(off) + 0] += blo((H).x) + blo((V).x);           \
  acc[(off) + 1] += bhi((H).x) + bhi((V).x);           \
  acc[(off) + 2] += blo((H).y) + blo((V).y);           \
  acc[(off) + 3] += bhi((H).y) + bhi((V).y);           \
  acc[(off) + 4] += blo((H).z) + blo((V).z);           \
  acc[(off) + 5] += bhi((H).z) + bhi((V).z);           \
  acc[(off) + 6] += blo((H).w) + blo((V).w);           \
  acc[(off) + 7] += bhi((H).w) + bhi((V).w);
    {
      int bm = batch[m];
      const unsigned short* hp = hin + (size_t)m * DD + cb;
      const unsigned short* vp = vnb + (size_t)bm * DD + cb;
      uint4 h0 = *(const uint4*)hp, h1 = *(const uint4*)(hp + 8);
      uint4 v0 = *(const uint4*)vp, v1 = *(const uint4*)(vp + 8);
      SET8(0, h0, v0) SET8(8, h1, v1)
    }
    int e = cnt[m];
    if (e > DEGMAX) e = DEGMAX;
    const int* ep = sspk + (size_t)m * DEGMAX;
    for (int t = 0; t < e; ++t) {
      int v = ep[t];
      int s = v & 0x1FFFF;
      int g = v >> 17;
      const unsigned short* hp = hin + (size_t)s * DD + cb;
      const unsigned short* vp = vnb + (size_t)g * DD + cb;
      uint4 h0 = *(const uint4*)hp, h1 = *(const uint4*)(hp + 8);
      uint4 v0 = *(const uint4*)vp, v1 = *(const uint4*)(vp + 8);
      ACC8(0, h0, v0) ACC8(8, h1, v1)
    }
#undef SET8
#undef ACC8
    // cols cb+i*8+j -> fragment [ks=q][lh=i][row=r][j]
#pragma unroll
    for (int i = 0; i < 2; ++i) {
      uint4 o;
      o.x = pack2(acc[i * 8 + 0], acc[i * 8 + 1]);
      o.y = pack2(acc[i * 8 + 2], acc[i * 8 + 3]);
      o.z = pack2(acc[i * 8 + 4], acc[i * 8 + 5]);
      o.w = pack2(acc[i * 8 + 6], acc[i * 8 + 7]);
      *(uint4*)&As[q][i][r][0] = o;
    }
  }
  __syncthreads();

  int wave = tid >> 6, lane = tid & 63;  // wave in [0,8)
  int lrow = lane & 31, lhi = lane >> 5;
  int c = wave * 32 + lrow;

  // ---- phase 2: hid = relu(z @ W1 + b1) -> Bs ----
  {
    floatx16 facc = (floatx16)(0.f);
    const bf16x8* wf = (const bf16x8*)Wf1;
#pragma unroll
    for (int ks = 0; ks < 16; ++ks) {
      bf16x8 a = *(const bf16x8*)&As[ks][lhi][lrow][0];
      bf16x8 bb = wf[((wave * 16 + ks) << 6) + lane];
      facc = __builtin_amdgcn_mfma_f32_32x32x16_bf16(a, bb, facc, 0, 0, 0);
    }
    int ks2 = c >> 4, lh2 = (c >> 3) & 1, j2 = c & 7;
    float shf = b1[c];
#pragma unroll
    for (int reg = 0; reg < 16; ++reg) {
      int row = (reg & 3) + ((reg >> 2) << 3) + (lhi << 2);
      Bs[ks2][lh2][row][j2] = f2bf(fmaxf(facc[reg] + shf, 0.f));
    }
  }
  __syncthreads();

  // ---- phase 3: h = leaky0.1(bn(hid @ W2 + b2)) -> global + pooled atomics ----
  {
    floatx16 facc = (floatx16)(0.f);
    const bf16x8* wf = (const bf16x8*)Wf2;
#pragma unroll
    for (int ks = 0; ks < 16; ++ks) {
      bf16x8 a = *(const bf16x8*)&Bs[ks][lhi][lrow][0];
      bf16x8 bb = wf[((wave * 16 + ks) << 6) + lane];
      facc = __builtin_amdgcn_mfma_f32_32x32x16_bf16(a, bb, facc, 0, 0, 0);
    }
    float s = bng[c] * rsqrtf(bnv[c] + BN_EPS);
    float shf = b2[c] * s + bnb[c] - bnm[c] * s;
    float run = 0.f;
    int gprev = gsh[lhi << 2];  // first row in this lane half's ascending set
#pragma unroll
    for (int reg = 0; reg < 16; ++reg) {
      int row = (reg & 3) + ((reg >> 2) << 3) + (lhi << 2);  // ascending
      float v = facc[reg] * s + shf;
      v = (v > 0.f) ? v : 0.1f * v;
      hout[(size_t)(m0 + row) * DD + c] = f2bf(v);
      int gg = gsh[row];
      if (gg != gprev) {
        atomicAdd(&t0f[(size_t)gprev * DD + c], run);
        run = 0.f;
        gprev = gg;
      }
      run += v;
    }
    atomicAdd(&t0f[(size_t)gprev * DD + c], run);
  }
}

// ------- fused vn MLP: vn = relu(bn2(relu(bn1((t0f+vn)@W1+b1))@W2+b2)) -------
// gin-style geometry: 512 thr, 32 rows/block, 63 blocks. Re-zeroes its own
// t0f rows (read by same thread before the zero -> no race; block-exclusive).
__global__ __launch_bounds__(512) void k_vn_mlp(
    float* __restrict__ t0f,
    const unsigned short* __restrict__ Wf1, const float* __restrict__ b1,
    const float* __restrict__ bn1g, const float* __restrict__ bn1b,
    const float* __restrict__ bn1m, const float* __restrict__ bn1v,
    const unsigned short* __restrict__ Wf2, const float* __restrict__ b2,
    const float* __restrict__ bn2g, const float* __restrict__ bn2b,
    const float* __restrict__ bn2m, const float* __restrict__ bn2v,
    unsigned short* __restrict__ vnb) {
  __shared__ unsigned short As[16][2][32][8];  // 16 KB
  __shared__ unsigned short Bs[16][2][32][8];  // 16 KB
  int tid = threadIdx.x;
  int m0 = blockIdx.x * 32;
  int r = tid >> 4, q = tid & 15;
  int m = m0 + r;
  int cb = q << 4;
  {
    uint4 wa = make_uint4(0u, 0u, 0u, 0u), wb = wa;
    if (m < NG) {
      float* tp = t0f + (size_t)m * DD + cb;
      float4 a0 = *(const float4*)tp;
      float4 a1 = *(const float4*)(tp + 4);
      float4 a2 = *(const float4*)(tp + 8);
      float4 a3 = *(const float4*)(tp + 12);
      const unsigned short* vp = vnb + (size_t)m * DD + cb;
      uint4 vv0 = *(const uint4*)vp;
      uint4 vv1 = *(const uint4*)(vp + 8);
      wa.x = pack2(a0.x + blo(vv0.x), a0.y + bhi(vv0.x));
      wa.y = pack2(a0.z + blo(vv0.y), a0.w + bhi(vv0.y));
      wa.z = pack2(a1.x + blo(vv0.z), a1.y + bhi(vv0.z));
      wa.w = pack2(a1.z + blo(vv0.w), a1.w + bhi(vv0.w));
      wb.x = pack2(a2.x + blo(vv1.x), a2.y + bhi(vv1.x));
      wb.y = pack2(a2.z + blo(vv1.y), a2.w + bhi(vv1.y));
      wb.z = pack2(a3.x + blo(vv1.z), a3.y + bhi(vv1.z));
      wb.w = pack2(a3.z + blo(vv1.w), a3.w + bhi(vv1.w));
      float4 z = make_float4(0.f, 0.f, 0.f, 0.f);
      *(float4*)tp = z;
      *(float4*)(tp + 4) = z;
      *(float4*)(tp + 8) = z;
      *(float4*)(tp + 12) = z;
    }
    *(uint4*)&As[q][0][r][0] = wa;
    *(uint4*)&As[q][1][r][0] = wb;
  }
  __syncthreads();

  int wave = tid >> 6, lane = tid & 63;
  int lrow = lane & 31, lhi = lane >> 5;
  int c = wave * 32 + lrow;

  // ---- phase 2: t1 = relu(bn1(t @ W1 + b1)) -> Bs ----
  {
    floatx16 facc = (floatx16)(0.f);
    const bf16x8* wf = (const bf16x8*)Wf1;
#pragma unroll
    for (int ks = 0; ks < 16; ++ks) {
      bf16x8 a = *(const bf16x8*)&As[ks][lhi][lrow][0];
      bf16x8 bb = wf[((wave * 16 + ks) << 6) + lane];
      facc = __builtin_amdgcn_mfma_f32_32x32x16_bf16(a, bb, facc, 0, 0, 0);
    }
    float s = bn1g[c] * rsqrtf(bn1v[c] + BN_EPS);
    float shf = b1[c] * s + bn1b[c] - bn1m[c] * s;
    int ks2 = c >> 4, lh2 = (c >> 3) & 1, j2 = c & 7;
#pragma unroll
    for (int reg = 0; reg < 16; ++reg) {
      int row = (reg & 3) + ((reg >> 2) << 3) + (lhi << 2);
      Bs[ks2][lh2][row][j2] = f2bf(fmaxf(facc[reg] * s + shf, 0.f));
    }
  }
  __syncthreads();

  // ---- phase 3: vn = relu(bn2(t1 @ W2 + b2)) -> global ----
  {
    floatx16 facc = (floatx16)(0.f);
    const bf16x8* wf = (const bf16x8*)Wf2;
#pragma unroll
    for (int ks = 0; ks < 16; ++ks) {
      bf16x8 a = *(const bf16x8*)&Bs[ks][lhi][lrow][0];
      bf16x8 bb = wf[((wave * 16 + ks) << 6) + lane];
      facc = __builtin_amdgcn_mfma_f32_32x32x16_bf16(a, bb, facc, 0, 0, 0);
    }
    float s = bn2g[c] * rsqrtf(bn2v[c] + BN_EPS);
    float shf = b2[c] * s + bn2b[c] - bn2m[c] * s;
#pragma unroll
    for (int reg = 0; reg < 16; ++reg) {
      int row = (reg & 3) + ((reg >> 2) << 3) + (lhi << 2);
      int mm = m0 + row;
      if (mm < NG)
        vnb[(size_t)mm * DD + c] = f2bf(fmaxf(facc[reg] * s + shf, 0.f));
    }
  }
}

// ---------------- fused head: out = relu(relu(g@W1+b1)@W2+b2)@W3+b3, all fp32 -------
__global__ __launch_bounds__(256) void k_head(
    const float* __restrict__ X,
    const float* __restrict__ w1, const float* __restrict__ b1,
    const float* __restrict__ w2, const float* __restrict__ b2,
    const float* __restrict__ w3, const float* __restrict__ b3,
    float* __restrict__ out) {
  __shared__ float Xs[32][260];
  __shared__ float Ws[8192];
  __shared__ float H1[32][132];
  __shared__ float H2[32][68];
  __shared__ float W3s[64][12];
  int tid = threadIdx.x;
  int m0 = blockIdx.x * 32;
#pragma unroll
  for (int i = 0; i < 8; ++i) {
    int p = i * 256 + tid;
    int r = p >> 6, c4 = (p & 63) << 2;
    float4 v = make_float4(0.f, 0.f, 0.f, 0.f);
    if (m0 + r < NG) v = *(const float4*)(X + (size_t)(m0 + r) * 256 + c4);
    *(float4*)&Xs[r][c4] = v;
  }
  for (int p = tid; p < 704; p += 256) W3s[p / 11][p % 11] = w3[p];

  int r0 = (tid >> 5) << 2;
  int c0 = (tid & 31) << 2;
  float a1[4][4] = {};
  for (int k0 = 0; k0 < 256; k0 += 64) {
    __syncthreads();
#pragma unroll
    for (int i = 0; i < 8; ++i) {
      int p = i * 256 + tid;
      int r = p >> 5, c4 = (p & 31) << 2;
      *(float4*)&Ws[r * 128 + c4] = *(const float4*)(w1 + (size_t)(k0 + r) * 128 + c4);
    }
    __syncthreads();
#pragma unroll 4
    for (int k = 0; k < 64; ++k) {
      float4 wv = *(float4*)&Ws[k * 128 + c0];
      float xv[4];
#pragma unroll
      for (int i = 0; i < 4; ++i) xv[i] = Xs[r0 + i][k0 + k];
#pragma unroll
      for (int i = 0; i < 4; ++i) {
        a1[i][0] = fmaf(xv[i], wv.x, a1[i][0]);
        a1[i][1] = fmaf(xv[i], wv.y, a1[i][1]);
        a1[i][2] = fmaf(xv[i], wv.z, a1[i][2]);
        a1[i][3] = fmaf(xv[i], wv.w, a1[i][3]);
      }
    }
  }
#pragma unroll
  for (int i = 0; i < 4; ++i) {
    float4 o;
    o.x = fmaxf(a1[i][0] + b1[c0 + 0], 0.f);
    o.y = fmaxf(a1[i][1] + b1[c0 + 1], 0.f);
    o.z = fmaxf(a1[i][2] + b1[c0 + 2], 0.f);
    o.w = fmaxf(a1[i][3] + b1[c0 + 3], 0.f);
    *(float4*)&H1[r0 + i][c0] = o;
  }
  __syncthreads();
#pragma unroll
  for (int i = 0; i < 8; ++i) {
    int p = i * 256 + tid;
    int r = p >> 4, c4 = (p & 15) << 2;
    *(float4*)&Ws[r * 64 + c4] = *(const float4*)(w2 + (size_t)r * 64 + c4);
  }
  __syncthreads();
  int r2 = (tid >> 4) << 1;
  int c2 = (tid & 15) << 2;
  float a2[2][4] = {};
#pragma unroll 4
  for (int k = 0; k < 128; ++k) {
    float4 wv = *(float4*)&Ws[k * 64 + c2];
    float x0 = H1[r2][k], x1 = H1[r2 + 1][k];
    a2[0][0] = fmaf(x0, wv.x, a2[0][0]);
    a2[0][1] = fmaf(x0, wv.y, a2[0][1]);
    a2[0][2] = fmaf(x0, wv.z, a2[0][2]);
    a2[0][3] = fmaf(x0, wv.w, a2[0][3]);
    a2[1][0] = fmaf(x1, wv.x, a2[1][0]);
    a2[1][1] = fmaf(x1, wv.y, a2[1][1]);
    a2[1][2] = fmaf(x1, wv.z, a2[1][2]);
    a2[1][3] = fmaf(x1, wv.w, a2[1][3]);
  }
#pragma unroll
  for (int i = 0; i < 2; ++i) {
    float4 o;
    o.x = fmaxf(a2[i][0] + b2[c2 + 0], 0.f);
    o.y = fmaxf(a2[i][1] + b2[c2 + 1], 0.f);
    o.z = fmaxf(a2[i][2] + b2[c2 + 2], 0.f);
    o.w = fmaxf(a2[i][3] + b2[c2 + 3], 0.f);
    *(float4*)&H2[r2 + i][c2] = o;
  }
  __syncthreads();
  for (int p = tid; p < 352; p += 256) {
    int r = p / 11, c = p - (p / 11) * 11;
    float acc = b3[c];
#pragma unroll 8
    for (int k = 0; k < 64; ++k) acc = fmaf(H2[r][k], W3s[k][c], acc);
    if (m0 + r < NG) out[(size_t)(m0 + r) * 11 + c] = acc;
  }
}

extern "C" void kernel_launch(void* const* d_in, const int* in_sizes, int n_in,
                              void* d_out, int out_size, void* d_ws, size_t ws_size,
                              hipStream_t stream) {
  const float* x      = (const float*)d_in[0];
  const int*   ei     = (const int*)d_in[1];
  const int*   batch  = (const int*)d_in[2];
  const float* node_w = (const float*)d_in[3];
  const float* node_b = (const float*)d_in[4];
  const float* vn_w   = (const float*)d_in[5];
  const float* gin_w1 = (const float*)d_in[6];
  const float* gin_b1 = (const float*)d_in[7];
  const float* gin_w2 = (const float*)d_in[8];
  const float* gin_b2 = (const float*)d_in[9];
  const float* bn_g   = (const float*)d_in[10];
  const float* bn_b   = (const float*)d_in[11];
  const float* bn_m   = (const float*)d_in[12];
  const float* bn_v   = (const float*)d_in[13];
  const float* vn_w1  = (const float*)d_in[14];
  const float* vn_b1  = (const float*)d_in[15];
  const float* vbn1g  = (const float*)d_in[16];
  const float* vbn1b  = (const float*)d_in[17];
  const float* vbn1m  = (const float*)d_in[18];
  const float* vbn1v  = (const float*)d_in[19];
  const float* vn_w2  = (const float*)d_in[20];
  const float* vn_b2  = (const float*)d_in[21];
  const float* vbn2g  = (const float*)d_in[22];
  const float* vbn2b  = (const float*)d_in[23];
  const float* vbn2m  = (const float*)d_in[24];
  const float* vbn2v  = (const float*)d_in[25];
  const float* head_w1 = (const float*)d_in[26];
  const float* head_b1 = (const float*)d_in[27];
  const float* head_w2 = (const float*)d_in[28];
  const float* head_b2 = (const float*)d_in[29];
  const float* head_w3 = (const float*)d_in[30];
  const float* head_b3 = (const float*)d_in[31];

  // ---- workspace layout (~122 MB) ----
  unsigned short* h16   = (unsigned short*)d_ws;          // [NN*DD] ping
  unsigned short* u16   = h16 + (size_t)NN * DD;          // [NN*DD] pong
  unsigned short* vnb   = u16 + (size_t)NN * DD;          // [NG*DD]
  unsigned short* wf1   = vnb + (size_t)NG * DD;          // [5*65536]
  unsigned short* wf2   = wf1 + 5 * 65536;                // [5*65536]
  unsigned short* wfv1  = wf2 + 5 * 65536;                // [4*65536]
  unsigned short* wfv2  = wfv1 + 4 * 65536;               // [4*65536]
  float* t0f   = (float*)(wfv2 + 4 * 65536);              // [NG*DD]
  int* sspk    = (int*)(t0f + (size_t)NG * DD);           // [NN*DEGMAX] 12.8MB
  int* cnt     = sspk + (size_t)NN * DEGMAX;              // [NN] (zeroed in pack)

  const int* src = ei;
  const int* dst = ei + NE;

  // ---- once per launch: weight pack + vn init + zeros; padded edge table ----
  const int AUXB = (NG * DD + NN + NG * DD + 255) / 256;
  k_pack_all<<<WBLK + AUXB, 256, 0, stream>>>(
      gin_w1, gin_w2, vn_w1, vn_w2, wf1, vn_w, vnb, cnt, t0f);
  k_fill_src<<<(NE + 255) / 256, 256, 0, stream>>>(src, dst, batch, cnt, sspk);

  unsigned short* hin = h16;
  unsigned short* hout = u16;
  k_node_encode<<<NN / 16, 256, 0, stream>>>(x, node_w, node_b, hin);

  const int GG_NN = NN / 32;          // 3125
  const int GM_NG = (NG + 31) / 32;   // 63

  for (int l = 0; l < NL; ++l) {
    // h_out = leaky(bn(relu(((h+vn)[m] + sum (h+vn)[src]) @W1+b1) @W2+b2));
    // pooled sums -> t0f atomics (t0f zeroed by pack_all / previous vn_mlp)
    k_gin_layer<<<GG_NN, 512, 0, stream>>>(
        hin, vnb, sspk, cnt, batch,
        wf1 + (size_t)l * 65536, gin_b1 + l * DD,
        wf2 + (size_t)l * 65536, gin_b2 + l * DD,
        bn_g + l * DD, bn_b + l * DD, bn_m + l * DD, bn_v + l * DD,
        hout, t0f);
    if (l < NL - 1) {
      // vn = mlp(t0f + vn); also re-zeroes t0f for the next layer
      k_vn_mlp<<<GM_NG, 512, 0, stream>>>(
          t0f,
          wfv1 + (size_t)l * 65536, vn_b1 + l * DD,
          vbn1g + l * DD, vbn1b + l * DD, vbn1m + l * DD, vbn1v + l * DD,
          wfv2 + (size_t)l * 65536, vn_b2 + l * DD,
          vbn2g + l * DD, vbn2b + l * DD, vbn2m + l * DD, vbn2v + l * DD,
          vnb);
    }
    unsigned short* tmp = hin; hin = hout; hout = tmp;
  }
  // head reads the last layer's pooled sums directly (f32, no vn)
  k_head<<<(NG + 31) / 32, 256, 0, stream>>>(
      t0f, head_w1, head_b1, head_w2, head_b2, head_w3, head_b3, (float*)d_out);
}